// Round 2
// baseline (202.772 us; speedup 1.0000x reference)
//
#include <hip/hip_runtime.h>
#include <math.h>
#include <stdint.h>

#define NROWS 4096
#define CDIM 1024
#define T0_LO 2000
#define T0_HI 10000
#define T1_LO 10000
#define ROOT_COLS 2002
#define ROOT_PAD 2048
#define T0_COLS 8000
#define T0_PAD 8064
#define T1_COLS 40257
#define T1_PAD 40320
#define HB_STRIDE 320
#define LOG2E 1.44269504088896340736f
#define LN2 0.69314718055994530942f

using short8  = __attribute__((ext_vector_type(8))) short;
using ushort8 = __attribute__((ext_vector_type(8))) unsigned short;
using floatx4 = __attribute__((ext_vector_type(4))) float;

__device__ __forceinline__ unsigned short f2bf(float x) {
  union { float f; unsigned int u; } v; v.f = x;
  unsigned int r = v.u + 0x7fffu + ((v.u >> 16) & 1u);
  return (unsigned short)(r >> 16);
}
__device__ __forceinline__ float bf2f(unsigned short h) {
  union { unsigned int u; float f; } v; v.u = ((unsigned int)h) << 16;
  return v.f;
}
__device__ __forceinline__ floatx4 mfma16(short8 a, short8 b, floatx4 c) {
  return __builtin_amdgcn_mfma_f32_16x16x32_bf16(a, b, c, 0, 0, 0);
}
// Async global->LDS 16B: lane i's data lands at lds_wave_base + i*16.
__device__ __forceinline__ void stage16(const unsigned short* g,
                                        unsigned short* lds_wave_base, int lane) {
#if __has_builtin(__builtin_amdgcn_global_load_lds)
  __builtin_amdgcn_global_load_lds(
      (const __attribute__((address_space(1))) void*)g,
      (__attribute__((address_space(3))) void*)lds_wave_base, 16, 0, 0);
#else
  ((ushort8*)lds_wave_base)[lane] = *(const ushort8*)g;
#endif
}

// ---------------- workspace layout (bytes) ----------------
static constexpr size_t B_HB  = 0;                          // ushort[4096*320]
static constexpr size_t B_LB  = B_HB + 4096ull * 320 * 2;   // ushort[4096*1024] bf16 logits
static constexpr size_t B_WP  = B_LB + 4096ull * 1024 * 2;  // ushort[384*1024] (rows 320..383 zero)
static constexpr size_t B_WH  = B_WP + 384ull * 1024 * 2;   // ushort[2048*1024]  (x log2e)
static constexpr size_t B_WS0 = B_WH + 2048ull * 1024 * 2;  // ushort[8064*256]   (x log2e, pad 64)
static constexpr size_t B_WS1 = B_WS0 + 8064ull * 256 * 2;  // ushort[40320*64]   (x log2e, pad 63)
static constexpr size_t B_S   = B_WS1 + 40320ull * 64 * 2;  // float[3*4096]
static constexpr size_t B_P   = B_S + 3ull * 4096 * 4;      // float[3*4096]
static constexpr size_t B_I0  = B_P + 3ull * 4096 * 4;
static constexpr size_t B_I1  = B_I0 + 4096ull * 4;
static constexpr size_t B_CNT = B_I1 + 4096ull * 4;

// 32x32 f32 tile transpose -> bf16 (x scale), shared by prep_a and mid.
__device__ __forceinline__ void transpose_tile(
    const float* __restrict__ W, unsigned short* __restrict__ Wt,
    int K, int N, int Npad, int nx, int rel, float scale,
    float (*tile)[33], int tid) {
  const int n0 = (rel % nx) * 32, k0 = (rel / nx) * 32;
  const int tx = tid & 31, ty = tid >> 5;  // 32 x 8
  for (int i = 0; i < 32; i += 8) {
    int k = k0 + ty + i, n = n0 + tx;
    tile[ty + i][tx] = (n < N) ? W[(size_t)k * N + n] * scale : 0.f;
  }
  __syncthreads();
  // vectorized write: each thread emits 4 consecutive k as one 8 B store
  const int nloc = tid >> 3, kg = tid & 7;
  const int n = n0 + nloc;
  if (n < Npad) {
    union { unsigned short v[4]; uint2 u; } x;
#pragma unroll
    for (int j = 0; j < 4; j++) x.v[j] = f2bf(tile[kg * 4 + j][nloc]);
    *(uint2*)&Wt[(size_t)n * K + k0 + kg * 4] = x.u;
  }
}

// ---------------- prep_a: Lb cast + Wp transpose + S zero + compact ----------
#define PA_LB_END   2048                     // logits cast
#define PA_WP0_END  (PA_LB_END + 256)        // proj0: 8 x 32
#define PA_WP1_END  (PA_WP0_END + 64)        // proj1: 2 x 32
#define PA_ZERO_END (PA_WP1_END + 32)        // Wp rows 320..383
#define PA_S_END    (PA_ZERO_END + 4)        // S zero
#define PA_TOTAL    (PA_S_END + 1)           // compact (single block)

__global__ __launch_bounds__(256) void prep_a_kernel(
    const float* __restrict__ proj0, const float* __restrict__ proj1,
    const float* __restrict__ logits, const int* __restrict__ targets,
    unsigned short* __restrict__ Wp, unsigned short* __restrict__ Lb,
    float* __restrict__ S, int* __restrict__ idx0, int* __restrict__ idx1,
    int* __restrict__ cnt) {
  __shared__ float tile[32][33];
  const int id = blockIdx.x, tid = threadIdx.x;
  if (id < PA_LB_END) {  // logits f32 -> bf16, 2048 elements/block
    size_t base = (size_t)id * 2048 + tid * 8;
    float4 v0 = *(const float4*)(logits + base);
    float4 v1 = *(const float4*)(logits + base + 4);
    ushort8 h;
    h[0] = f2bf(v0.x); h[1] = f2bf(v0.y); h[2] = f2bf(v0.z); h[3] = f2bf(v0.w);
    h[4] = f2bf(v1.x); h[5] = f2bf(v1.y); h[6] = f2bf(v1.z); h[7] = f2bf(v1.w);
    *(ushort8*)(Lb + base) = h;
    return;
  }
  if (id < PA_WP1_END) {  // proj0 / proj1 transpose into Wp
    if (id < PA_WP0_END)
      transpose_tile(proj0, Wp, 1024, 256, 256, 8, id - PA_LB_END, 1.f, tile, tid);
    else
      transpose_tile(proj1, Wp + 256 * 1024, 1024, 64, 64, 2, id - PA_WP0_END,
                     1.f, tile, tid);
    return;
  }
  if (id < PA_ZERO_END) {  // zero Wp rows 320..383
    size_t off = (size_t)(id - PA_WP1_END) * 2048 + tid * 8;
    ushort8 z = {0, 0, 0, 0, 0, 0, 0, 0};
    *(ushort8*)(Wp + 320ull * 1024 + off) = z;
    return;
  }
  if (id < PA_S_END) {  // zero S (12288 floats over 4 blocks)
    int rel = id - PA_ZERO_END;
    float4 z = make_float4(0.f, 0.f, 0.f, 0.f);
#pragma unroll
    for (int j = 0; j < 3; j++)
      ((float4*)S)[rel * 768 + j * 256 + tid] = z;
    return;
  }
  // compact: one block, LDS counters (cnt written only here)
  __shared__ int base2[2];
  if (tid < 2) base2[tid] = 0;
  __syncthreads();
  for (int n = tid; n < NROWS; n += 256) {
    int t = targets[n];
    if (t >= T0_LO && t < T0_HI) idx0[atomicAdd(&base2[0], 1)] = n;
    else if (t >= T1_LO)         idx1[atomicAdd(&base2[1], 1)] = n;
  }
  __syncthreads();
  if (tid < 2) cnt[tid] = base2[tid];
}

// Shared 64-row x CI-cg x K=1024 MFMA K-loop (double-buffered KC=128 halves).
template<int CI>
__device__ __forceinline__ void gemm64_kloop(
    unsigned short* A_lds,   // 2 x (64*128) ushorts = 32 KB
    const unsigned short* Arow,
    const unsigned short* const (&Bbase)[CI],
    floatx4 (&acc)[CI][4], int tid) {
  const int lane = tid & 63, w = tid >> 6;
  const int m = lane & 15, quad = lane >> 4, keym = m & 7;
  int goff[4];
#pragma unroll
  for (int it = 0; it < 4; it++) {
    int s = w * 256 + it * 64 + lane;
    int r = s >> 4, p = s & 15;
    int cq = p ^ (r & 7);
    goff[it] = r * CDIM + cq * 8;
  }
#pragma unroll
  for (int it = 0; it < 4; it++)
    stage16(Arow + goff[it], &A_lds[(w * 256 + it * 64) * 8], lane);
  for (int h = 0; h < 8; h++) {
    unsigned short* cur = A_lds + (h & 1) * (64 * 128);
    unsigned short* nxt = A_lds + ((h + 1) & 1) * (64 * 128);
    __syncthreads();
    if (h + 1 < 8) {
#pragma unroll
      for (int it = 0; it < 4; it++)
        stage16(Arow + goff[it] + (h + 1) * 128,
                &nxt[(w * 256 + it * 64) * 8], lane);
    }
    short8 b[CI][4];
#pragma unroll
    for (int ci = 0; ci < CI; ci++)
#pragma unroll
      for (int ks = 0; ks < 4; ks++)
        b[ci][ks] = *(const short8*)(Bbase[ci] + h * 128 + ks * 32);
    short8 areg[4][4];
#pragma unroll
    for (int t = 0; t < 4; t++)
#pragma unroll
      for (int ks = 0; ks < 4; ks++) {
        int ch = ((ks << 2) + quad) ^ keym;
        areg[t][ks] = *(const short8*)&cur[(t * 16 + m) * 128 + (ch << 3)];
      }
#pragma unroll
    for (int ci = 0; ci < CI; ci++)
#pragma unroll
      for (int ks = 0; ks < 4; ks++)
#pragma unroll
        for (int t = 0; t < 4; t++)
          acc[ci][t] = mfma16(areg[t][ks], b[ci][ks], acc[ci][t]);
  }
}

// ---------------- mid kernel: gemm_hidden blocks + Wh/Ws0/Ws1 transposes ----
// r16: hidden (320 blocks, ~1.25/CU alone) now overlaps the 6.6k transpose
// blocks instead of running on an idle machine.
#define K2_HID      320
#define K2_WH_END   (K2_HID + 2048)
#define K2_WS0_END  (K2_WH_END + 2016)
#define K2_TOTAL    (K2_WS0_END + 2520)

__global__ __launch_bounds__(256) void mid_kernel(
    const float* __restrict__ head, const float* __restrict__ scale0,
    const float* __restrict__ scale1,
    const unsigned short* __restrict__ Lb, const unsigned short* __restrict__ Wp,
    unsigned short* __restrict__ Wh, unsigned short* __restrict__ Ws0,
    unsigned short* __restrict__ Ws1, unsigned short* __restrict__ Hb) {
  __shared__ __align__(16) unsigned char smem2[32768];
  const int id = blockIdx.x, tid = threadIdx.x;
  if (id < K2_HID) {  // hidden: Hb[4096][320] = bf16(Lb @ Wp)
    // XCD swizzle: each XCD owns 8 row-slices (1 MB Lb, L2-resident x5 cgs).
    const int xcd = id & 7, k = id >> 3;          // k in [0,40)
    const int row0 = (xcd * 8 + (k & 7)) * 64;
    const int cg0 = k >> 3;                       // [0,5)
    unsigned short* A_lds = (unsigned short*)smem2;
    const int lane = tid & 63, w = tid >> 6;
    const int m = lane & 15, quad = lane >> 4;
    const floatx4 zf = {0.f, 0.f, 0.f, 0.f};
    floatx4 acc[1][4];
#pragma unroll
    for (int t = 0; t < 4; t++) acc[0][t] = zf;
    const unsigned short* Bb[1] = {
        Wp + (size_t)(cg0 * 64 + w * 16 + m) * CDIM + quad * 8};
    gemm64_kloop<1>(A_lds, Lb + (size_t)row0 * CDIM, Bb, acc, tid);
    int n = cg0 * 64 + w * 16 + m;
    if (n < HB_STRIDE) {
#pragma unroll
      for (int t = 0; t < 4; t++)
#pragma unroll
        for (int r = 0; r < 4; r++)
          Hb[(size_t)(row0 + t * 16 + quad * 4 + r) * HB_STRIDE + n] =
              f2bf(acc[0][t][r]);
    }
    return;
  }
  const float* W; unsigned short* Wt; int K, N, Npad, nx, rel; float scale;
  int t = id - K2_HID;
  if (t < 2048)      { W = head;   Wt = Wh;  K = 1024; N = ROOT_COLS; Npad = ROOT_PAD; scale = LOG2E; nx = 64;   rel = t; }
  else if (t < 4064) { W = scale0; Wt = Ws0; K = 256;  N = T0_COLS;   Npad = T0_PAD;   scale = LOG2E; nx = 252;  rel = t - 2048; }
  else               { W = scale1; Wt = Ws1; K = 64;   N = T1_COLS;   Npad = T1_PAD;   scale = LOG2E; nx = 1260; rel = t - 4064; }
  transpose_tile(W, Wt, K, N, Npad, nx, rel, scale, (float(*)[33])smem2, tid);
}

// ---------------- mega kernel: root CE + tail1 + tail0 + picked ----------------
// r16: PATH-INTERLEAVED XCD schedule. r15's remap halved FETCH (66->38 MB,
// now ~= the one-pass ideal) and killed bank conflicts, but dur didn't move:
// the paths ran as serialized phases (root MFMA-phase with VALU idle, then
// tail exp2-phase with MFMA idle, then picked as a pure HBM-latency tail).
// Each XCD's 588 blocks now arrive as repeating groups of 9:
//   {1 root, 1 T1, 5 T0, 2 picked}
// so every CU co-hosts MFMA-heavy, VALU-heavy and latency-heavy waves (m114
// pipe overlap), and picked's HBM latency hides under GEMM compute.
#define MG_ROOT 512           // 32 x-tiles (BM=128) x 16 cg-pairs
#define MG_T1   480           // 32 row-tiles (BM=128) x 15 y
#define MG_T0   2688          // 128 row-tiles x 21 y
#define MG_PICK 1024
#define MG_TOTAL (MG_ROOT + MG_T1 + MG_T0 + MG_PICK)

// Root CE, BM=128, KC=64 ping-pong double-buffer.
__device__ __forceinline__ void root_compute(
    const unsigned short* cur, const short8 (&b)[2][2], floatx4 (&acc)[2][8],
    int m, int quad, int keym) {
#pragma unroll
  for (int hf = 0; hf < 2; hf++) {
    short8 areg[4][2];
#pragma unroll
    for (int t = 0; t < 4; t++)
#pragma unroll
      for (int ks = 0; ks < 2; ks++) {
        int ch = ((ks << 2) + quad) ^ keym;
        areg[t][ks] = *(const short8*)&cur[(hf * 64 + t * 16 + m) * 64 + (ch << 3)];
      }
#pragma unroll
    for (int ci = 0; ci < 2; ci++)
#pragma unroll
      for (int ks = 0; ks < 2; ks++)
#pragma unroll
        for (int t = 0; t < 4; t++)
          acc[ci][hf * 4 + t] = mfma16(areg[t][ks], b[ci][ks], acc[ci][hf * 4 + t]);
  }
}

__device__ __forceinline__ void root_stage(
    const unsigned short* Arow, const int (&goff)[4], int koff,
    unsigned short* buf, int w, int lane) {
#pragma unroll
  for (int it = 0; it < 4; it++)
    stage16(Arow + goff[it] + koff, &buf[(it * 256 + w * 64) * 8], lane);
}

__device__ __forceinline__ void root_loadB(
    const unsigned short* const (&Bb)[2], int koff, short8 (&b)[2][2]) {
#pragma unroll
  for (int ci = 0; ci < 2; ci++)
#pragma unroll
    for (int ks = 0; ks < 2; ks++)
      b[ci][ks] = *(const short8*)(Bb[ci] + koff + ks * 32);
}

__device__ __forceinline__ void root_path(
    unsigned char* smem, int bx, int by,
    const unsigned short* __restrict__ Lb,
    const unsigned short* __restrict__ Wh, float* __restrict__ S) {
  unsigned short* bufA = (unsigned short*)smem;   // 128 rows x 64 k = 16 KB
  unsigned short* bufB = bufA + 128 * 64;         // second half
  const int tid = threadIdx.x;
  const int row0 = bx * 128;
  const int cg0 = by * 2;
  const int lane = tid & 63, w = tid >> 6;
  const int m = lane & 15, quad = lane >> 4, keym = m & 7;
  const floatx4 zf = {0.f, 0.f, 0.f, 0.f};
  floatx4 acc[2][8];
#pragma unroll
  for (int ci = 0; ci < 2; ci++)
#pragma unroll
    for (int t = 0; t < 8; t++) acc[ci][t] = zf;
  const unsigned short* Bb[2] = {
      Wh + (size_t)((cg0 + 0) * 64 + w * 16 + m) * CDIM + quad * 8,
      Wh + (size_t)((cg0 + 1) * 64 + w * 16 + m) * CDIM + quad * 8};
  const unsigned short* Arow = Lb + (size_t)row0 * CDIM;
  // staging: slot s = it*256 + w*64 + lane -> row r = s>>3 (8 chunks/row of
  // 16 B), phys p = s&7 stores logical cq = p^(r&7) (XOR bank swizzle)
  int goff[4];
#pragma unroll
  for (int it = 0; it < 4; it++) {
    int s = it * 256 + w * 64 + lane;
    int r = s >> 3, p = s & 7;
    int cq = p ^ (r & 7);
    goff[it] = r * CDIM + cq * 8;
  }
  short8 b0[2][2], b1[2][2];
  root_stage(Arow, goff, 0, bufA, w, lane);   // chunk 0 in flight
  root_loadB(Bb, 0, b0);
  for (int hh = 0; hh < 8; hh++) {
    __syncthreads();                          // drains chunk 2hh into bufA
    root_stage(Arow, goff, (hh * 2 + 1) * 64, bufB, w, lane);
    root_loadB(Bb, (hh * 2 + 1) * 64, b1);
    root_compute(bufA, b0, acc, m, quad, keym);
    __syncthreads();                          // drains chunk 2hh+1 into bufB
    if (hh < 7) {
      root_stage(Arow, goff, (hh * 2 + 2) * 64, bufA, w, lane);
      root_loadB(Bb, (hh * 2 + 2) * 64, b0);
    }
    root_compute(bufB, b1, acc, m, quad, keym);
  }
  // epilogue: reuse smem for 128 per-row sums
  __syncthreads();
  float* sums = (float*)smem;
  if (tid < 128) sums[tid] = 0.f;
  __syncthreads();
#pragma unroll
  for (int t = 0; t < 8; t++)
#pragma unroll
    for (int r = 0; r < 4; r++) {
      float e = __builtin_amdgcn_exp2f(acc[0][t][r]) +
                __builtin_amdgcn_exp2f(acc[1][t][r]);
      e += __shfl_xor(e, 1); e += __shfl_xor(e, 2);
      e += __shfl_xor(e, 4); e += __shfl_xor(e, 8);
      if (m == 0)
        atomicAdd(&sums[(t >> 2) * 64 + (t & 3) * 16 + quad * 4 + r], e);
    }
  __syncthreads();
  if (tid < 128) atomicAdd(&S[row0 + tid], sums[tid]);
}

// Tail CE path: A in regs, runtime cg loop, 2 cgs/iter through literally-
// indexed b0/b1 with 2-deep prefetch.
template<int K, int TILES, int MODE>
__device__ __forceinline__ void tail_path(
    unsigned char* smem, int bx, int by,
    const unsigned short* __restrict__ Hb, int acol0,
    const unsigned short* __restrict__ Wt, int ncgpb,
    const int* __restrict__ idx, const int* __restrict__ cnt,
    float* __restrict__ S) {
  constexpr int BM = TILES * 16;
  constexpr int CpR = K / 8;
  constexpr int KS = K / 32;
  unsigned short* A_lds = (unsigned short*)smem;            // BM*K ushorts
  int* row_lds = (int*)(smem + (size_t)BM * K * 2);
  float* sum_lds = (float*)(smem + (size_t)BM * K * 2 + BM * 4);
  const int tid = threadIdx.x;
  const int count = cnt[MODE - 1];
  const int row0 = bx * BM;
  if (row0 >= count) return;
  if (tid < BM) {
    int r = row0 + tid;
    row_lds[tid] = (r < count) ? idx[r] : -1;
    sum_lds[tid] = 0.f;
  }
  __syncthreads();
#pragma unroll
  for (int i = 0; i < BM * CpR / 256; i++) {
    int c = tid + 256 * i;
    int rl = c / CpR, cq = c % CpR;
    int row = row_lds[rl];
    ushort8 v = {0, 0, 0, 0, 0, 0, 0, 0};
    if (row >= 0) v = *(const ushort8*)(Hb + (size_t)row * HB_STRIDE + acol0 + cq * 8);
    *(ushort8*)&A_lds[rl * K + ((cq ^ (rl & 7)) << 3)] = v;
  }
  __syncthreads();
  const int lane = tid & 63, w = tid >> 6;
  const int m = lane & 15, quad = lane >> 4, keym = m & 7;
  const floatx4 zf = {0.f, 0.f, 0.f, 0.f};
  short8 areg[TILES][KS];
#pragma unroll
  for (int t = 0; t < TILES; t++)
#pragma unroll
    for (int ks = 0; ks < KS; ks++) {
      int ch = ((ks << 2) + quad) ^ keym;
      areg[t][ks] = *(const short8*)&A_lds[(t * 16 + m) * K + (ch << 3)];
    }
  float runsum[TILES][4];
#pragma unroll
  for (int t = 0; t < TILES; t++)
#pragma unroll
    for (int r = 0; r < 4; r++) runsum[t][r] = 0.f;

  const int cg0 = by * ncgpb;
  const unsigned short* Bp = Wt + (size_t)(cg0 * 64 + w * 16 + m) * K + quad * 8;
  short8 b0[KS], b1[KS];
#pragma unroll
  for (int ks = 0; ks < KS; ks++) b0[ks] = *(const short8*)(Bp + ks * 32);
#pragma unroll
  for (int ks = 0; ks < KS; ks++)
    b1[ks] = *(const short8*)(Bp + (size_t)64 * K + ks * 32);

  for (int cc = 0; cc < ncgpb; cc += 2) {  // runtime loop, literal reg indices
    floatx4 acc[TILES];
#pragma unroll
    for (int t = 0; t < TILES; t++) acc[t] = zf;
#pragma unroll
    for (int ks = 0; ks < KS; ks++)
#pragma unroll
      for (int t = 0; t < TILES; t++) acc[t] = mfma16(areg[t][ks], b0[ks], acc[t]);
    if (cc + 2 < ncgpb) {
      const unsigned short* p = Bp + (size_t)(cc + 2) * 64 * K;
#pragma unroll
      for (int ks = 0; ks < KS; ks++) b0[ks] = *(const short8*)(p + ks * 32);
    }
#pragma unroll
    for (int t = 0; t < TILES; t++)
#pragma unroll
      for (int r = 0; r < 4; r++)
        runsum[t][r] += __builtin_amdgcn_exp2f(acc[t][r]);

#pragma unroll
    for (int t = 0; t < TILES; t++) acc[t] = zf;
#pragma unroll
    for (int ks = 0; ks < KS; ks++)
#pragma unroll
      for (int t = 0; t < TILES; t++) acc[t] = mfma16(areg[t][ks], b1[ks], acc[t]);
    if (cc + 3 < ncgpb) {
      const unsigned short* p = Bp + (size_t)(cc + 3) * 64 * K;
#pragma unroll
      for (int ks = 0; ks < KS; ks++) b1[ks] = *(const short8*)(p + ks * 32);
    }
#pragma unroll
    for (int t = 0; t < TILES; t++)
#pragma unroll
      for (int r = 0; r < 4; r++)
        runsum[t][r] += __builtin_amdgcn_exp2f(acc[t][r]);
  }

#pragma unroll
  for (int t = 0; t < TILES; t++)
#pragma unroll
    for (int r = 0; r < 4; r++) {
      float e = runsum[t][r];
      e += __shfl_xor(e, 1); e += __shfl_xor(e, 2);
      e += __shfl_xor(e, 4); e += __shfl_xor(e, 8);
      if (m == 0) atomicAdd(&sum_lds[t * 16 + quad * 4 + r], e);
    }
  __syncthreads();
  if (tid < BM) {
    int row = row_lds[tid];
    if (row >= 0) atomicAdd(&S[row], sum_lds[tid]);
  }
}

__device__ __forceinline__ void picked_path(
    int rel, const float* __restrict__ logits, const int* __restrict__ targets,
    const unsigned short* __restrict__ Wh,
    const unsigned short* __restrict__ Ws0,
    const unsigned short* __restrict__ Ws1,
    const unsigned short* __restrict__ Hb, float* __restrict__ P) {
  const int tid = threadIdx.x, lane = tid & 63;
  const int row = rel * 4 + (tid >> 6);
  const int t = targets[row];
  const int tr = (t >= T0_LO && t < T0_HI) ? T0_LO : ((t >= T1_LO) ? T0_LO + 1 : t);
  const float* a = logits + (size_t)row * CDIM + lane * 16;
  const unsigned short* wr = Wh + (size_t)tr * CDIM + lane * 16;
  float acc = 0.f;
#pragma unroll
  for (int q = 0; q < 2; q++) {
    ushort8 wv = *(const ushort8*)(wr + q * 8);
    float4 a0 = ((const float4*)a)[q * 2];
    float4 a1 = ((const float4*)a)[q * 2 + 1];
    acc += a0.x * bf2f(wv[0]) + a0.y * bf2f(wv[1]) + a0.z * bf2f(wv[2]) + a0.w * bf2f(wv[3]);
    acc += a1.x * bf2f(wv[4]) + a1.y * bf2f(wv[5]) + a1.z * bf2f(wv[6]) + a1.w * bf2f(wv[7]);
  }
#pragma unroll
  for (int off = 1; off < 64; off <<= 1) acc += __shfl_xor(acc, off);
  if (lane == 0) P[row] = acc * LN2;
  if (t >= T0_LO) {
    float acc2 = 0.f;
    if (t < T0_HI) {
      const unsigned short* h = Hb + (size_t)row * HB_STRIDE + lane * 4;
      const unsigned short* w2 = Ws0 + (size_t)(t - T0_LO) * 256 + lane * 4;
#pragma unroll
      for (int j = 0; j < 4; j++) acc2 += bf2f(h[j]) * bf2f(w2[j]);
    } else {
      acc2 = bf2f(Hb[(size_t)row * HB_STRIDE + 256 + lane]) *
             bf2f(Ws1[(size_t)(t - T1_LO) * 64 + lane]);
    }
#pragma unroll
    for (int off = 1; off < 64; off <<= 1) acc2 += __shfl_xor(acc2, off);
    if (lane == 0) P[(t < T0_HI ? NROWS : 2 * NROWS) + row] = acc2 * LN2;
  }
}

__global__ __launch_bounds__(256, 2) void mega_kernel(
    const unsigned short* __restrict__ Lb,
    const unsigned short* __restrict__ Wh,
    const unsigned short* __restrict__ Ws0,
    const unsigned short* __restrict__ Ws1,
    const unsigned short* __restrict__ Hb,
    const float* __restrict__ logits, const int* __restrict__ targets,
    const int* __restrict__ idx0, const int* __restrict__ idx1,
    const int* __restrict__ cnt, float* __restrict__ S, float* __restrict__ P) {
  __shared__ __align__(16) unsigned char smem[32768];
  const int bid = blockIdx.x;
  const int xcd = bid & 7, l = bid >> 3;  // per-XCD local, NLOC = 588
  // groups of 9: {root, T1, T0 x5, picked x2}; tail 12 locals -> T0.
  int path, k;
  if (l < 576) {
    int g = l / 9, r = l - g * 9;
    if (r == 0)      { path = 0; k = g; }
    else if (r == 1) { if (g < 60) { path = 1; k = g; }
                       else        { path = 2; k = 320 + (g - 60); } }
    else if (r <= 6) { path = 2; k = g * 5 + (r - 2); }
    else             { path = 3; k = g * 2 + (r - 7); }
  } else {
    path = 2; k = 324 + (l - 576);
  }
  if (path == 0) {
    int wk = xcd * 64 + k;                       // [0,512) bijective
    root_path(smem, wk >> 4, wk & 15, Lb, Wh, S);
  } else if (path == 1) {
    int wk = xcd * 60 + k;                       // [0,480) bijective
    tail_path<64, 8, 2>(smem, wk & 31, wk >> 5, Hb, 256, Ws1, 42, idx1, cnt,
                        S + 2 * NROWS);
  } else if (path == 2) {
    int wk = xcd * 336 + k;                      // [0,2688) bijective
    tail_path<256, 2, 1>(smem, wk & 127, wk >> 7, Hb, 0, Ws0, 6, idx0, cnt,
                         S + NROWS);
  } else {
    picked_path(xcd * 128 + k, logits, targets, Wh, Ws0, Ws1, Hb, P);
  }
}

__global__ __launch_bounds__(1024) void loss_kernel(
    const int* __restrict__ targets,
    const float* __restrict__ S,   // [3][NROWS]
    const float* __restrict__ P,   // [3][NROWS]
    float* __restrict__ out) {
  const int tid = threadIdx.x;
  float sr = 0.f, s0 = 0.f, s1 = 0.f, c0 = 0.f, c1 = 0.f;
  for (int n = tid; n < NROWS; n += 1024) {
    int t = targets[n];
    sr += logf(S[n] - 46.f) - P[n];  // 46 root pad cols -> exp2(0)=1 each
    if (t >= T0_LO && t < T0_HI) { s0 += logf(S[NROWS + n] - 64.f) - P[NROWS + n]; c0 += 1.f; }
    else if (t >= T1_LO)         { s1 += logf(S[2 * NROWS + n] - 63.f) - P[2 * NROWS + n]; c1 += 1.f; }
  }
  for (int off = 32; off > 0; off >>= 1) {
    sr += __shfl_down(sr, off);
    s0 += __shfl_down(s0, off);
    s1 += __shfl_down(s1, off);
    c0 += __shfl_down(c0, off);
    c1 += __shfl_down(c1, off);
  }
  __shared__ float red[16][5];
  int wv = tid >> 6;
  if ((tid & 63) == 0) { red[wv][0] = sr; red[wv][1] = s0; red[wv][2] = s1; red[wv][3] = c0; red[wv][4] = c1; }
  __syncthreads();
  if (tid == 0) {
    sr = 0.f; s0 = 0.f; s1 = 0.f; c0 = 0.f; c1 = 0.f;
#pragma unroll
    for (int i = 0; i < 16; i++) {
      sr += red[i][0]; s0 += red[i][1]; s1 += red[i][2];
      c0 += red[i][3]; c1 += red[i][4];
    }
    float root_loss = sr / (float)NROWS;
    float l0 = s0 / fmaxf(c0, 1.f);
    float l1 = s1 / fmaxf(c1, 1.f);
    out[0] = (root_loss + l0 + l1) / 3.f;
  }
}

extern "C" void kernel_launch(void* const* d_in, const int* in_sizes, int n_in,
                              void* d_out, int out_size, void* d_ws, size_t ws_size,
                              hipStream_t stream) {
  const float* logits  = (const float*)d_in[0];
  const int*   targets = (const int*)d_in[1];
  const float* head    = (const float*)d_in[2];
  const float* proj0   = (const float*)d_in[3];
  const float* scale0  = (const float*)d_in[4];
  const float* proj1   = (const float*)d_in[5];
  const float* scale1  = (const float*)d_in[6];
  float* out = (float*)d_out;
  char* ws = (char*)d_ws;

  unsigned short* Hb  = (unsigned short*)(ws + B_HB);
  unsigned short* Lb  = (unsigned short*)(ws + B_LB);
  unsigned short* Wp  = (unsigned short*)(ws + B_WP);
  unsigned short* Wh  = (unsigned short*)(ws + B_WH);
  unsigned short* Ws0 = (unsigned short*)(ws + B_WS0);
  unsigned short* Ws1 = (unsigned short*)(ws + B_WS1);
  float* S = (float*)(ws + B_S);
  float* P = (float*)(ws + B_P);
  int* idx0 = (int*)(ws + B_I0);
  int* idx1 = (int*)(ws + B_I1);
  int* cnt  = (int*)(ws + B_CNT);

  prep_a_kernel<<<PA_TOTAL, 256, 0, stream>>>(proj0, proj1, logits, targets,
                                              Wp, Lb, S, idx0, idx1, cnt);
  mid_kernel<<<K2_TOTAL, 256, 0, stream>>>(head, scale0, scale1, Lb, Wp,
                                           Wh, Ws0, Ws1, Hb);
  mega_kernel<<<MG_TOTAL, 256, 0, stream>>>(Lb, Wh, Ws0, Ws1, Hb, logits,
                                            targets, idx0, idx1, cnt, S, P);
  loss_kernel<<<1, 1024, 0, stream>>>(targets, S, P, out);
}

// Round 3
// 196.967 us; speedup vs baseline: 1.0295x; 1.0295x over previous
//
#include <hip/hip_runtime.h>
#include <math.h>
#include <stdint.h>

#define NROWS 4096
#define CDIM 1024
#define T0_LO 2000
#define T0_HI 10000
#define T1_LO 10000
#define ROOT_COLS 2002
#define ROOT_PAD 2048
#define T0_COLS 8000
#define T0_PAD 8064
#define T1_COLS 40257
#define T1_PAD 40320
#define HB_STRIDE 320
#define LOG2E 1.44269504088896340736f
#define LN2 0.69314718055994530942f

using short8  = __attribute__((ext_vector_type(8))) short;
using ushort8 = __attribute__((ext_vector_type(8))) unsigned short;
using floatx4 = __attribute__((ext_vector_type(4))) float;

__device__ __forceinline__ unsigned short f2bf(float x) {
  union { float f; unsigned int u; } v; v.f = x;
  unsigned int r = v.u + 0x7fffu + ((v.u >> 16) & 1u);
  return (unsigned short)(r >> 16);
}
__device__ __forceinline__ float bf2f(unsigned short h) {
  union { unsigned int u; float f; } v; v.u = ((unsigned int)h) << 16;
  return v.f;
}
__device__ __forceinline__ floatx4 mfma16(short8 a, short8 b, floatx4 c) {
  return __builtin_amdgcn_mfma_f32_16x16x32_bf16(a, b, c, 0, 0, 0);
}
// Async global->LDS 16B: lane i's data lands at lds_wave_base + i*16.
__device__ __forceinline__ void stage16(const unsigned short* g,
                                        unsigned short* lds_wave_base, int lane) {
#if __has_builtin(__builtin_amdgcn_global_load_lds)
  __builtin_amdgcn_global_load_lds(
      (const __attribute__((address_space(1))) void*)g,
      (__attribute__((address_space(3))) void*)lds_wave_base, 16, 0, 0);
#else
  ((ushort8*)lds_wave_base)[lane] = *(const ushort8*)g;
#endif
}

// ---------------- workspace layout (bytes) ----------------
static constexpr size_t B_HB  = 0;                          // ushort[4096*320]
static constexpr size_t B_LB  = B_HB + 4096ull * 320 * 2;   // ushort[4096*1024] bf16 logits
static constexpr size_t B_WP  = B_LB + 4096ull * 1024 * 2;  // ushort[384*1024] (rows 320..383 zero)
static constexpr size_t B_WH  = B_WP + 384ull * 1024 * 2;   // ushort[2048*1024]  (x log2e)
static constexpr size_t B_WS0 = B_WH + 2048ull * 1024 * 2;  // ushort[8064*256]   (x log2e, pad 64)
static constexpr size_t B_WS1 = B_WS0 + 8064ull * 256 * 2;  // ushort[40320*64]   (x log2e, pad 63)
static constexpr size_t B_S   = B_WS1 + 40320ull * 64 * 2;  // float[3*4096]
static constexpr size_t B_P   = B_S + 3ull * 4096 * 4;      // float[3*4096]
static constexpr size_t B_I0  = B_P + 3ull * 4096 * 4;
static constexpr size_t B_I1  = B_I0 + 4096ull * 4;
static constexpr size_t B_CNT = B_I1 + 4096ull * 4;

// 32x32 f32 tile transpose -> bf16 (x scale), shared by prep_a and mid.
__device__ __forceinline__ void transpose_tile(
    const float* __restrict__ W, unsigned short* __restrict__ Wt,
    int K, int N, int Npad, int nx, int rel, float scale,
    float (*tile)[33], int tid) {
  const int n0 = (rel % nx) * 32, k0 = (rel / nx) * 32;
  const int tx = tid & 31, ty = tid >> 5;  // 32 x 8
  for (int i = 0; i < 32; i += 8) {
    int k = k0 + ty + i, n = n0 + tx;
    tile[ty + i][tx] = (n < N) ? W[(size_t)k * N + n] * scale : 0.f;
  }
  __syncthreads();
  // vectorized write: each thread emits 4 consecutive k as one 8 B store
  const int nloc = tid >> 3, kg = tid & 7;
  const int n = n0 + nloc;
  if (n < Npad) {
    union { unsigned short v[4]; uint2 u; } x;
#pragma unroll
    for (int j = 0; j < 4; j++) x.v[j] = f2bf(tile[kg * 4 + j][nloc]);
    *(uint2*)&Wt[(size_t)n * K + k0 + kg * 4] = x.u;
  }
}

// ---------------- prep_a: Lb cast + Wp transpose + S zero + compact ----------
#define PA_LB_END   2048                     // logits cast
#define PA_WP0_END  (PA_LB_END + 256)        // proj0: 8 x 32
#define PA_WP1_END  (PA_WP0_END + 64)        // proj1: 2 x 32
#define PA_ZERO_END (PA_WP1_END + 32)        // Wp rows 320..383
#define PA_S_END    (PA_ZERO_END + 4)        // S zero
#define PA_TOTAL    (PA_S_END + 1)           // compact (single block)

__global__ __launch_bounds__(256) void prep_a_kernel(
    const float* __restrict__ proj0, const float* __restrict__ proj1,
    const float* __restrict__ logits, const int* __restrict__ targets,
    unsigned short* __restrict__ Wp, unsigned short* __restrict__ Lb,
    float* __restrict__ S, int* __restrict__ idx0, int* __restrict__ idx1,
    int* __restrict__ cnt) {
  __shared__ float tile[32][33];
  const int id = blockIdx.x, tid = threadIdx.x;
  if (id < PA_LB_END) {  // logits f32 -> bf16, 2048 elements/block
    size_t base = (size_t)id * 2048 + tid * 8;
    float4 v0 = *(const float4*)(logits + base);
    float4 v1 = *(const float4*)(logits + base + 4);
    ushort8 h;
    h[0] = f2bf(v0.x); h[1] = f2bf(v0.y); h[2] = f2bf(v0.z); h[3] = f2bf(v0.w);
    h[4] = f2bf(v1.x); h[5] = f2bf(v1.y); h[6] = f2bf(v1.z); h[7] = f2bf(v1.w);
    *(ushort8*)(Lb + base) = h;
    return;
  }
  if (id < PA_WP1_END) {  // proj0 / proj1 transpose into Wp
    if (id < PA_WP0_END)
      transpose_tile(proj0, Wp, 1024, 256, 256, 8, id - PA_LB_END, 1.f, tile, tid);
    else
      transpose_tile(proj1, Wp + 256 * 1024, 1024, 64, 64, 2, id - PA_WP0_END,
                     1.f, tile, tid);
    return;
  }
  if (id < PA_ZERO_END) {  // zero Wp rows 320..383
    size_t off = (size_t)(id - PA_WP1_END) * 2048 + tid * 8;
    ushort8 z = {0, 0, 0, 0, 0, 0, 0, 0};
    *(ushort8*)(Wp + 320ull * 1024 + off) = z;
    return;
  }
  if (id < PA_S_END) {  // zero S (12288 floats over 4 blocks)
    int rel = id - PA_ZERO_END;
    float4 z = make_float4(0.f, 0.f, 0.f, 0.f);
#pragma unroll
    for (int j = 0; j < 3; j++)
      ((float4*)S)[rel * 768 + j * 256 + tid] = z;
    return;
  }
  // compact: one block, LDS counters (cnt written only here)
  __shared__ int base2[2];
  if (tid < 2) base2[tid] = 0;
  __syncthreads();
  for (int n = tid; n < NROWS; n += 256) {
    int t = targets[n];
    if (t >= T0_LO && t < T0_HI) idx0[atomicAdd(&base2[0], 1)] = n;
    else if (t >= T1_LO)         idx1[atomicAdd(&base2[1], 1)] = n;
  }
  __syncthreads();
  if (tid < 2) cnt[tid] = base2[tid];
}

// Shared 64-row x CI-cg x K=1024 MFMA K-loop (double-buffered KC=128 halves).
template<int CI>
__device__ __forceinline__ void gemm64_kloop(
    unsigned short* A_lds,   // 2 x (64*128) ushorts = 32 KB
    const unsigned short* Arow,
    const unsigned short* const (&Bbase)[CI],
    floatx4 (&acc)[CI][4], int tid) {
  const int lane = tid & 63, w = tid >> 6;
  const int m = lane & 15, quad = lane >> 4, keym = m & 7;
  int goff[4];
#pragma unroll
  for (int it = 0; it < 4; it++) {
    int s = w * 256 + it * 64 + lane;
    int r = s >> 4, p = s & 15;
    int cq = p ^ (r & 7);
    goff[it] = r * CDIM + cq * 8;
  }
#pragma unroll
  for (int it = 0; it < 4; it++)
    stage16(Arow + goff[it], &A_lds[(w * 256 + it * 64) * 8], lane);
  for (int h = 0; h < 8; h++) {
    unsigned short* cur = A_lds + (h & 1) * (64 * 128);
    unsigned short* nxt = A_lds + ((h + 1) & 1) * (64 * 128);
    __syncthreads();
    if (h + 1 < 8) {
#pragma unroll
      for (int it = 0; it < 4; it++)
        stage16(Arow + goff[it] + (h + 1) * 128,
                &nxt[(w * 256 + it * 64) * 8], lane);
    }
    short8 b[CI][4];
#pragma unroll
    for (int ci = 0; ci < CI; ci++)
#pragma unroll
      for (int ks = 0; ks < 4; ks++)
        b[ci][ks] = *(const short8*)(Bbase[ci] + h * 128 + ks * 32);
    short8 areg[4][4];
#pragma unroll
    for (int t = 0; t < 4; t++)
#pragma unroll
      for (int ks = 0; ks < 4; ks++) {
        int ch = ((ks << 2) + quad) ^ keym;
        areg[t][ks] = *(const short8*)&cur[(t * 16 + m) * 128 + (ch << 3)];
      }
#pragma unroll
    for (int ci = 0; ci < CI; ci++)
#pragma unroll
      for (int ks = 0; ks < 4; ks++)
#pragma unroll
        for (int t = 0; t < 4; t++)
          acc[ci][t] = mfma16(areg[t][ks], b[ci][ks], acc[ci][t]);
  }
}

// ---------------- mid kernel: gemm_hidden blocks + Wh/Ws0/Ws1 transposes ----
#define K2_HID      320
#define K2_WH_END   (K2_HID + 2048)
#define K2_WS0_END  (K2_WH_END + 2016)
#define K2_TOTAL    (K2_WS0_END + 2520)

__global__ __launch_bounds__(256) void mid_kernel(
    const float* __restrict__ head, const float* __restrict__ scale0,
    const float* __restrict__ scale1,
    const unsigned short* __restrict__ Lb, const unsigned short* __restrict__ Wp,
    unsigned short* __restrict__ Wh, unsigned short* __restrict__ Ws0,
    unsigned short* __restrict__ Ws1, unsigned short* __restrict__ Hb) {
  __shared__ __align__(16) unsigned char smem2[32768];
  const int id = blockIdx.x, tid = threadIdx.x;
  if (id < K2_HID) {  // hidden: Hb[4096][320] = bf16(Lb @ Wp)
    const int xcd = id & 7, k = id >> 3;          // k in [0,40)
    const int row0 = (xcd * 8 + (k & 7)) * 64;
    const int cg0 = k >> 3;                       // [0,5)
    unsigned short* A_lds = (unsigned short*)smem2;
    const int lane = tid & 63, w = tid >> 6;
    const int m = lane & 15, quad = lane >> 4;
    const floatx4 zf = {0.f, 0.f, 0.f, 0.f};
    floatx4 acc[1][4];
#pragma unroll
    for (int t = 0; t < 4; t++) acc[0][t] = zf;
    const unsigned short* Bb[1] = {
        Wp + (size_t)(cg0 * 64 + w * 16 + m) * CDIM + quad * 8};
    gemm64_kloop<1>(A_lds, Lb + (size_t)row0 * CDIM, Bb, acc, tid);
    int n = cg0 * 64 + w * 16 + m;
    if (n < HB_STRIDE) {
#pragma unroll
      for (int t = 0; t < 4; t++)
#pragma unroll
        for (int r = 0; r < 4; r++)
          Hb[(size_t)(row0 + t * 16 + quad * 4 + r) * HB_STRIDE + n] =
              f2bf(acc[0][t][r]);
    }
    return;
  }
  const float* W; unsigned short* Wt; int K, N, Npad, nx, rel; float scale;
  int t = id - K2_HID;
  if (t < 2048)      { W = head;   Wt = Wh;  K = 1024; N = ROOT_COLS; Npad = ROOT_PAD; scale = LOG2E; nx = 64;   rel = t; }
  else if (t < 4064) { W = scale0; Wt = Ws0; K = 256;  N = T0_COLS;   Npad = T0_PAD;   scale = LOG2E; nx = 252;  rel = t - 2048; }
  else               { W = scale1; Wt = Ws1; K = 64;   N = T1_COLS;   Npad = T1_PAD;   scale = LOG2E; nx = 1260; rel = t - 4064; }
  transpose_tile(W, Wt, K, N, Npad, nx, rel, scale, (float(*)[33])smem2, tid);
}

// ---------------- mega kernel v3: slim-register, 4 blocks/CU ----------------
// r17: r16's interleave FAILED (93 us, FETCH 2x): occupancy was reg-capped at
// 2 blocks/CU (VGPR 100 + 64 AGPR ~ 164) so path-mixing only thrashed L2.
// v3: every path <=128 total regs, __launch_bounds__(256,4) -> 4 blocks/CU;
// phases SORTED (r15 order, ideal FETCH) with enough blocks per phase:
//   picked 1024 | root BM=64 -> 1024 | t1 BM=64 grid-stride | t0 1-cg K-split
// t1/t0 dynamically pack active tiles over fixed bids (no dead-block churn).
#define MG_PICK 1024
#define MG_ROOT 1024
#define MG_T1   512
#define MG_T0   1024
#define MG_TOTAL (MG_PICK + MG_ROOT + MG_T1 + MG_T0)

// ---- root: BM=64, NC=128 (2 cgs), KC=64 ping-pong in 2 x 8 KB ----
__device__ __forceinline__ void root_compute64(
    const unsigned short* cur, const short8 (&b)[2][2], floatx4 (&acc)[2][4],
    int m, int quad, int keym) {
  short8 areg[4][2];
#pragma unroll
  for (int t = 0; t < 4; t++)
#pragma unroll
    for (int ks = 0; ks < 2; ks++) {
      int ch = ((ks << 2) + quad) ^ keym;
      areg[t][ks] = *(const short8*)&cur[(t * 16 + m) * 64 + (ch << 3)];
    }
#pragma unroll
  for (int ci = 0; ci < 2; ci++)
#pragma unroll
    for (int ks = 0; ks < 2; ks++)
#pragma unroll
      for (int t = 0; t < 4; t++)
        acc[ci][t] = mfma16(areg[t][ks], b[ci][ks], acc[ci][t]);
}

__device__ __forceinline__ void root_stage64(
    const unsigned short* Arow, const int (&goff)[2], int koff,
    unsigned short* buf, int w, int lane) {
#pragma unroll
  for (int it = 0; it < 2; it++)
    stage16(Arow + goff[it] + koff, &buf[(it * 256 + w * 64) * 8], lane);
}

__device__ __forceinline__ void root_loadB64(
    const unsigned short* const (&Bb)[2], int koff, short8 (&b)[2][2]) {
#pragma unroll
  for (int ci = 0; ci < 2; ci++)
#pragma unroll
    for (int ks = 0; ks < 2; ks++)
      b[ci][ks] = *(const short8*)(Bb[ci] + koff + ks * 32);
}

__device__ __forceinline__ void root_path64(
    unsigned char* smem, int bx, int by,
    const unsigned short* __restrict__ Lb,
    const unsigned short* __restrict__ Wh, float* __restrict__ S) {
  unsigned short* bufA = (unsigned short*)smem;   // 64 rows x 64 k = 8 KB
  unsigned short* bufB = bufA + 64 * 64;
  const int tid = threadIdx.x;
  const int row0 = bx * 64, cg0 = by * 2;
  const int lane = tid & 63, w = tid >> 6;
  const int m = lane & 15, quad = lane >> 4, keym = m & 7;
  const floatx4 zf = {0.f, 0.f, 0.f, 0.f};
  floatx4 acc[2][4];
#pragma unroll
  for (int ci = 0; ci < 2; ci++)
#pragma unroll
    for (int t = 0; t < 4; t++) acc[ci][t] = zf;
  const unsigned short* Bb[2] = {
      Wh + (size_t)((cg0 + 0) * 64 + w * 16 + m) * CDIM + quad * 8,
      Wh + (size_t)((cg0 + 1) * 64 + w * 16 + m) * CDIM + quad * 8};
  const unsigned short* Arow = Lb + (size_t)row0 * CDIM;
  // slot s = it*256 + w*64 + lane -> row r = s>>3 (8 x 16B chunks/row),
  // phys p = s&7 stores logical cq = p^(r&7) (XOR bank swizzle)
  int goff[2];
#pragma unroll
  for (int it = 0; it < 2; it++) {
    int s = it * 256 + w * 64 + lane;
    int r = s >> 3, p = s & 7;
    int cq = p ^ (r & 7);
    goff[it] = r * CDIM + cq * 8;
  }
  short8 b0[2][2], b1[2][2];
  root_stage64(Arow, goff, 0, bufA, w, lane);   // chunk 0 in flight
  root_loadB64(Bb, 0, b0);
  for (int hh = 0; hh < 8; hh++) {
    __syncthreads();                            // drains chunk 2hh into bufA
    root_stage64(Arow, goff, (hh * 2 + 1) * 64, bufB, w, lane);
    root_loadB64(Bb, (hh * 2 + 1) * 64, b1);
    root_compute64(bufA, b0, acc, m, quad, keym);
    __syncthreads();                            // drains chunk 2hh+1 into bufB
    if (hh < 7) {
      root_stage64(Arow, goff, (hh * 2 + 2) * 64, bufA, w, lane);
      root_loadB64(Bb, (hh * 2 + 2) * 64, b0);
    }
    root_compute64(bufB, b1, acc, m, quad, keym);
  }
  // epilogue: 64 per-row sums in smem
  __syncthreads();
  float* sums = (float*)smem;
  if (tid < 64) sums[tid] = 0.f;
  __syncthreads();
#pragma unroll
  for (int t = 0; t < 4; t++)
#pragma unroll
    for (int r = 0; r < 4; r++) {
      float e = __builtin_amdgcn_exp2f(acc[0][t][r]) +
                __builtin_amdgcn_exp2f(acc[1][t][r]);
      e += __shfl_xor(e, 1); e += __shfl_xor(e, 2);
      e += __shfl_xor(e, 4); e += __shfl_xor(e, 8);
      if (m == 0) atomicAdd(&sums[t * 16 + quad * 4 + r], e);
    }
  __syncthreads();
  if (tid < 64) atomicAdd(&S[row0 + tid], sums[tid]);
}

// ---- t1: BM=64 TILES=4, K=64, 42 cgs/work, grid-stride over nx1*15 works ---
__device__ __forceinline__ void t1_loop(
    unsigned char* smem, int rel, const unsigned short* __restrict__ Hb,
    const unsigned short* __restrict__ Ws1, const int* __restrict__ idx,
    const int* __restrict__ cnt, float* __restrict__ S) {
  constexpr int BM = 64, K = 64, NCG = 42;
  unsigned short* A_lds = (unsigned short*)smem;            // 8 KB
  int* row_lds = (int*)(smem + BM * K * 2);
  float* sum_lds = (float*)(smem + BM * K * 2 + BM * 4);
  const int tid = threadIdx.x;
  const int count = cnt[1];
  const int nx = (count + 63) >> 6;
  const int nworks = nx * 15;
  const int lane = tid & 63, w = tid >> 6;
  const int m = lane & 15, quad = lane >> 4, keym = m & 7;
  const floatx4 zf = {0.f, 0.f, 0.f, 0.f};
  for (int wk = rel; wk < nworks; wk += MG_T1) {
    const int by = wk / nx, bx = wk - by * nx;
    __syncthreads();   // previous iteration's LDS readers done
    if (tid < BM) {
      int r = bx * BM + tid;
      row_lds[tid] = (r < count) ? idx[r] : -1;
      sum_lds[tid] = 0.f;
    }
    __syncthreads();
#pragma unroll
    for (int i = 0; i < 2; i++) {   // BM * (K/8) / 256
      int c = tid + 256 * i;
      int rl = c >> 3, cq = c & 7;
      int row = row_lds[rl];
      ushort8 v = {0, 0, 0, 0, 0, 0, 0, 0};
      if (row >= 0)
        v = *(const ushort8*)(Hb + (size_t)row * HB_STRIDE + 256 + cq * 8);
      *(ushort8*)&A_lds[rl * K + ((cq ^ (rl & 7)) << 3)] = v;
    }
    __syncthreads();
    short8 areg[4][2];
#pragma unroll
    for (int t = 0; t < 4; t++)
#pragma unroll
      for (int ks = 0; ks < 2; ks++) {
        int ch = ((ks << 2) + quad) ^ keym;
        areg[t][ks] = *(const short8*)&A_lds[(t * 16 + m) * K + (ch << 3)];
      }
    float runsum[4][4];
#pragma unroll
    for (int t = 0; t < 4; t++)
#pragma unroll
      for (int r = 0; r < 4; r++) runsum[t][r] = 0.f;
    const unsigned short* Bp =
        Ws1 + (size_t)(by * NCG * 64 + w * 16 + m) * K + quad * 8;
    short8 b0[2], b1[2];
#pragma unroll
    for (int ks = 0; ks < 2; ks++) b0[ks] = *(const short8*)(Bp + ks * 32);
#pragma unroll
    for (int ks = 0; ks < 2; ks++)
      b1[ks] = *(const short8*)(Bp + (size_t)64 * K + ks * 32);
    for (int cc = 0; cc < NCG; cc += 2) {
      floatx4 acc[4];
#pragma unroll
      for (int t = 0; t < 4; t++) acc[t] = zf;
#pragma unroll
      for (int ks = 0; ks < 2; ks++)
#pragma unroll
        for (int t = 0; t < 4; t++) acc[t] = mfma16(areg[t][ks], b0[ks], acc[t]);
      if (cc + 2 < NCG) {
        const unsigned short* p = Bp + (size_t)(cc + 2) * 64 * K;
#pragma unroll
        for (int ks = 0; ks < 2; ks++) b0[ks] = *(const short8*)(p + ks * 32);
      }
#pragma unroll
      for (int t = 0; t < 4; t++)
#pragma unroll
        for (int r = 0; r < 4; r++)
          runsum[t][r] += __builtin_amdgcn_exp2f(acc[t][r]);
#pragma unroll
      for (int t = 0; t < 4; t++) acc[t] = zf;
#pragma unroll
      for (int ks = 0; ks < 2; ks++)
#pragma unroll
        for (int t = 0; t < 4; t++) acc[t] = mfma16(areg[t][ks], b1[ks], acc[t]);
      if (cc + 3 < NCG) {
        const unsigned short* p = Bp + (size_t)(cc + 3) * 64 * K;
#pragma unroll
        for (int ks = 0; ks < 2; ks++) b1[ks] = *(const short8*)(p + ks * 32);
      }
#pragma unroll
      for (int t = 0; t < 4; t++)
#pragma unroll
        for (int r = 0; r < 4; r++)
          runsum[t][r] += __builtin_amdgcn_exp2f(acc[t][r]);
    }
#pragma unroll
    for (int t = 0; t < 4; t++)
#pragma unroll
      for (int r = 0; r < 4; r++) {
        float e = runsum[t][r];
        e += __shfl_xor(e, 1); e += __shfl_xor(e, 2);
        e += __shfl_xor(e, 4); e += __shfl_xor(e, 8);
        if (m == 0) atomicAdd(&sum_lds[t * 16 + quad * 4 + r], e);
      }
    __syncthreads();
    if (tid < BM) {
      int row = row_lds[tid];
      if (row >= 0) atomicAdd(&S[2 * NROWS + row], sum_lds[tid]);
    }
  }
}

// ---- t0: BM=32 TILES=2, K=256 in two reg-halves, 1 cg/work, nx0*126 works --
__device__ __forceinline__ void t0_loop(
    unsigned char* smem, int rel, const unsigned short* __restrict__ Hb,
    const unsigned short* __restrict__ Ws0, const int* __restrict__ idx,
    const int* __restrict__ cnt, float* __restrict__ S) {
  constexpr int BM = 32, K = 256;
  unsigned short* A_lds = (unsigned short*)smem;            // 16 KB
  int* row_lds = (int*)(smem + BM * K * 2);
  float* sum_lds = (float*)(smem + BM * K * 2 + BM * 4);
  const int tid = threadIdx.x;
  const int count = cnt[0];
  const int nx = (count + 31) >> 5;
  const int nworks = nx * 126;
  const int lane = tid & 63, w = tid >> 6;
  const int m = lane & 15, quad = lane >> 4, keym = m & 7;
  const floatx4 zf = {0.f, 0.f, 0.f, 0.f};
  for (int wk = rel; wk < nworks; wk += MG_T0) {
    const int by = wk / nx, bx = wk - by * nx;
    __syncthreads();
    if (tid < BM) {
      int r = bx * BM + tid;
      row_lds[tid] = (r < count) ? idx[r] : -1;
      sum_lds[tid] = 0.f;
    }
    __syncthreads();
#pragma unroll
    for (int i = 0; i < 4; i++) {   // BM * (K/8) / 256
      int c = tid + 256 * i;
      int rl = c >> 5, cq = c & 31;
      int row = row_lds[rl];
      ushort8 v = {0, 0, 0, 0, 0, 0, 0, 0};
      if (row >= 0)
        v = *(const ushort8*)(Hb + (size_t)row * HB_STRIDE + cq * 8);
      *(ushort8*)&A_lds[rl * K + ((cq ^ (rl & 7)) << 3)] = v;
    }
    __syncthreads();
    const unsigned short* Bp =
        Ws0 + (size_t)(by * 64 + w * 16 + m) * K + quad * 8;
    floatx4 acc[2] = {zf, zf};
#pragma unroll
    for (int half = 0; half < 2; half++) {   // K split: areg/b reloaded
      short8 b[4], areg[2][4];
#pragma unroll
      for (int ks = 0; ks < 4; ks++)
        b[ks] = *(const short8*)(Bp + half * 128 + ks * 32);
#pragma unroll
      for (int t = 0; t < 2; t++)
#pragma unroll
        for (int ks = 0; ks < 4; ks++) {
          int ch = (((half * 4 + ks) << 2) + quad) ^ keym;   // [0,32)
          areg[t][ks] = *(const short8*)&A_lds[(t * 16 + m) * K + (ch << 3)];
        }
#pragma unroll
      for (int ks = 0; ks < 4; ks++)
#pragma unroll
        for (int t = 0; t < 2; t++)
          acc[t] = mfma16(areg[t][ks], b[ks], acc[t]);
    }
#pragma unroll
    for (int t = 0; t < 2; t++)
#pragma unroll
      for (int r = 0; r < 4; r++) {
        float e = __builtin_amdgcn_exp2f(acc[t][r]);
        e += __shfl_xor(e, 1); e += __shfl_xor(e, 2);
        e += __shfl_xor(e, 4); e += __shfl_xor(e, 8);
        if (m == 0) atomicAdd(&sum_lds[t * 16 + quad * 4 + r], e);
      }
    __syncthreads();
    if (tid < BM) {
      int row = row_lds[tid];
      if (row >= 0) atomicAdd(&S[NROWS + row], sum_lds[tid]);
    }
  }
}

__device__ __forceinline__ void picked_path(
    int rel, const float* __restrict__ logits, const int* __restrict__ targets,
    const unsigned short* __restrict__ Wh,
    const unsigned short* __restrict__ Ws0,
    const unsigned short* __restrict__ Ws1,
    const unsigned short* __restrict__ Hb, float* __restrict__ P) {
  const int tid = threadIdx.x, lane = tid & 63;
  const int row = rel * 4 + (tid >> 6);
  const int t = targets[row];
  const int tr = (t >= T0_LO && t < T0_HI) ? T0_LO : ((t >= T1_LO) ? T0_LO + 1 : t);
  const float* a = logits + (size_t)row * CDIM + lane * 16;
  const unsigned short* wr = Wh + (size_t)tr * CDIM + lane * 16;
  float acc = 0.f;
#pragma unroll
  for (int q = 0; q < 2; q++) {
    ushort8 wv = *(const ushort8*)(wr + q * 8);
    float4 a0 = ((const float4*)a)[q * 2];
    float4 a1 = ((const float4*)a)[q * 2 + 1];
    acc += a0.x * bf2f(wv[0]) + a0.y * bf2f(wv[1]) + a0.z * bf2f(wv[2]) + a0.w * bf2f(wv[3]);
    acc += a1.x * bf2f(wv[4]) + a1.y * bf2f(wv[5]) + a1.z * bf2f(wv[6]) + a1.w * bf2f(wv[7]);
  }
#pragma unroll
  for (int off = 1; off < 64; off <<= 1) acc += __shfl_xor(acc, off);
  if (lane == 0) P[row] = acc * LN2;
  if (t >= T0_LO) {
    float acc2 = 0.f;
    if (t < T0_HI) {
      const unsigned short* h = Hb + (size_t)row * HB_STRIDE + lane * 4;
      const unsigned short* w2 = Ws0 + (size_t)(t - T0_LO) * 256 + lane * 4;
#pragma unroll
      for (int j = 0; j < 4; j++) acc2 += bf2f(h[j]) * bf2f(w2[j]);
    } else {
      acc2 = bf2f(Hb[(size_t)row * HB_STRIDE + 256 + lane]) *
             bf2f(Ws1[(size_t)(t - T1_LO) * 64 + lane]);
    }
#pragma unroll
    for (int off = 1; off < 64; off <<= 1) acc2 += __shfl_xor(acc2, off);
    if (lane == 0) P[(t < T0_HI ? NROWS : 2 * NROWS) + row] = acc2 * LN2;
  }
}

__global__ __launch_bounds__(256, 4) void mega_kernel(
    const unsigned short* __restrict__ Lb,
    const unsigned short* __restrict__ Wh,
    const unsigned short* __restrict__ Ws0,
    const unsigned short* __restrict__ Ws1,
    const unsigned short* __restrict__ Hb,
    const float* __restrict__ logits, const int* __restrict__ targets,
    const int* __restrict__ idx0, const int* __restrict__ idx1,
    const int* __restrict__ cnt, float* __restrict__ S, float* __restrict__ P) {
  __shared__ __align__(16) unsigned char smem[16640];
  int bid = blockIdx.x;
  if (bid < MG_PICK) {  // thin, leads while root ramps
    picked_path((bid & 7) * 128 + (bid >> 3), logits, targets, Wh, Ws0, Ws1,
                Hb, P);
    return;
  }
  bid -= MG_PICK;
  if (bid < MG_ROOT) {
    // per XCD: 8 x-slices (0.5 MB Lb resident) x 16 y, x-fastest
    const int xcd = bid & 7, j = bid >> 3;
    root_path64(smem, xcd * 8 + (j & 7), j >> 3, Lb, Wh, S);
    return;
  }
  bid -= MG_ROOT;
  if (bid < MG_T1) {
    t1_loop(smem, bid, Hb, Ws1, idx1, cnt, S);
    return;
  }
  bid -= MG_T1;
  t0_loop(smem, bid, Hb, Ws0, idx0, cnt, S);
}

__global__ __launch_bounds__(1024) void loss_kernel(
    const int* __restrict__ targets,
    const float* __restrict__ S,   // [3][NROWS]
    const float* __restrict__ P,   // [3][NROWS]
    float* __restrict__ out) {
  const int tid = threadIdx.x;
  float sr = 0.f, s0 = 0.f, s1 = 0.f, c0 = 0.f, c1 = 0.f;
  for (int n = tid; n < NROWS; n += 1024) {
    int t = targets[n];
    sr += logf(S[n] - 46.f) - P[n];  // 46 root pad cols -> exp2(0)=1 each
    if (t >= T0_LO && t < T0_HI) { s0 += logf(S[NROWS + n] - 64.f) - P[NROWS + n]; c0 += 1.f; }
    else if (t >= T1_LO)         { s1 += logf(S[2 * NROWS + n] - 63.f) - P[2 * NROWS + n]; c1 += 1.f; }
  }
  for (int off = 32; off > 0; off >>= 1) {
    sr += __shfl_down(sr, off);
    s0 += __shfl_down(s0, off);
    s1 += __shfl_down(s1, off);
    c0 += __shfl_down(c0, off);
    c1 += __shfl_down(c1, off);
  }
  __shared__ float red[16][5];
  int wv = tid >> 6;
  if ((tid & 63) == 0) { red[wv][0] = sr; red[wv][1] = s0; red[wv][2] = s1; red[wv][3] = c0; red[wv][4] = c1; }
  __syncthreads();
  if (tid == 0) {
    sr = 0.f; s0 = 0.f; s1 = 0.f; c0 = 0.f; c1 = 0.f;
#pragma unroll
    for (int i = 0; i < 16; i++) {
      sr += red[i][0]; s0 += red[i][1]; s1 += red[i][2];
      c0 += red[i][3]; c1 += red[i][4];
    }
    float root_loss = sr / (float)NROWS;
    float l0 = s0 / fmaxf(c0, 1.f);
    float l1 = s1 / fmaxf(c1, 1.f);
    out[0] = (root_loss + l0 + l1) / 3.f;
  }
}

extern "C" void kernel_launch(void* const* d_in, const int* in_sizes, int n_in,
                              void* d_out, int out_size, void* d_ws, size_t ws_size,
                              hipStream_t stream) {
  const float* logits  = (const float*)d_in[0];
  const int*   targets = (const int*)d_in[1];
  const float* head    = (const float*)d_in[2];
  const float* proj0   = (const float*)d_in[3];
  const float* scale0  = (const float*)d_in[4];
  const float* proj1   = (const float*)d_in[5];
  const float* scale1  = (const float*)d_in[6];
  float* out = (float*)d_out;
  char* ws = (char*)d_ws;

  unsigned short* Hb  = (unsigned short*)(ws + B_HB);
  unsigned short* Lb  = (unsigned short*)(ws + B_LB);
  unsigned short* Wp  = (unsigned short*)(ws + B_WP);
  unsigned short* Wh  = (unsigned short*)(ws + B_WH);
  unsigned short* Ws0 = (unsigned short*)(ws + B_WS0);
  unsigned short* Ws1 = (unsigned short*)(ws + B_WS1);
  float* S = (float*)(ws + B_S);
  float* P = (float*)(ws + B_P);
  int* idx0 = (int*)(ws + B_I0);
  int* idx1 = (int*)(ws + B_I1);
  int* cnt  = (int*)(ws + B_CNT);

  prep_a_kernel<<<PA_TOTAL, 256, 0, stream>>>(proj0, proj1, logits, targets,
                                              Wp, Lb, S, idx0, idx1, cnt);
  mid_kernel<<<K2_TOTAL, 256, 0, stream>>>(head, scale0, scale1, Lb, Wp,
                                           Wh, Ws0, Ws1, Hb);
  mega_kernel<<<MG_TOTAL, 256, 0, stream>>>(Lb, Wh, Ws0, Ws1, Hb, logits,
                                            targets, idx0, idx1, cnt, S, P);
  loss_kernel<<<1, 1024, 0, stream>>>(targets, S, P, out);
}

// Round 5
// 185.176 us; speedup vs baseline: 1.0950x; 1.0637x over previous
//
#include <hip/hip_runtime.h>
#include <math.h>
#include <stdint.h>

#define NROWS 4096
#define CDIM 1024
#define T0_LO 2000
#define T0_HI 10000
#define T1_LO 10000
#define ROOT_COLS 2002
#define ROOT_PAD 2048
#define T0_COLS 8000
#define T0_PAD 8064
#define T1_COLS 40257
#define T1_PAD 40320
#define HB_STRIDE 320
#define LOG2E 1.44269504088896340736f
#define LN2 0.69314718055994530942f

using short8  = __attribute__((ext_vector_type(8))) short;
using ushort8 = __attribute__((ext_vector_type(8))) unsigned short;
using floatx4 = __attribute__((ext_vector_type(4))) float;

__device__ __forceinline__ unsigned short f2bf(float x) {
  union { float f; unsigned int u; } v; v.f = x;
  unsigned int r = v.u + 0x7fffu + ((v.u >> 16) & 1u);
  return (unsigned short)(r >> 16);
}
__device__ __forceinline__ float bf2f(unsigned short h) {
  union { unsigned int u; float f; } v; v.u = ((unsigned int)h) << 16;
  return v.f;
}
__device__ __forceinline__ floatx4 mfma16(short8 a, short8 b, floatx4 c) {
  return __builtin_amdgcn_mfma_f32_16x16x32_bf16(a, b, c, 0, 0, 0);
}
// Async global->LDS 16B: lane i's data lands at lds_wave_base + i*16.
__device__ __forceinline__ void stage16(const unsigned short* g,
                                        unsigned short* lds_wave_base, int lane) {
#if __has_builtin(__builtin_amdgcn_global_load_lds)
  __builtin_amdgcn_global_load_lds(
      (const __attribute__((address_space(1))) void*)g,
      (__attribute__((address_space(3))) void*)lds_wave_base, 16, 0, 0);
#else
  ((ushort8*)lds_wave_base)[lane] = *(const ushort8*)g;
#endif
}

// ---------------- workspace layout (bytes) ----------------
static constexpr size_t B_HB  = 0;                          // ushort[4096*320]
static constexpr size_t B_LB  = B_HB + 4096ull * 320 * 2;   // ushort[4096*1024] bf16 logits
static constexpr size_t B_WP  = B_LB + 4096ull * 1024 * 2;  // ushort[384*1024] (rows 320..383 zero)
static constexpr size_t B_WH  = B_WP + 384ull * 1024 * 2;   // ushort[2048*1024]  (x log2e)
static constexpr size_t B_WS0 = B_WH + 2048ull * 1024 * 2;  // ushort[8064*256]   (x log2e, pad 64)
static constexpr size_t B_WS1 = B_WS0 + 8064ull * 256 * 2;  // ushort[40320*64]   (x log2e, pad 63)
static constexpr size_t B_S   = B_WS1 + 40320ull * 64 * 2;  // float[3*4096]
static constexpr size_t B_P   = B_S + 3ull * 4096 * 4;      // float[3*4096]
static constexpr size_t B_I0  = B_P + 3ull * 4096 * 4;
static constexpr size_t B_I1  = B_I0 + 4096ull * 4;
static constexpr size_t B_CNT = B_I1 + 4096ull * 4;

// 32x32 f32 tile transpose -> bf16 (x scale).
// r19: r18's store phase lacked the tid<128 guard (nloc ran to 63 -> OOB tile
// reads + 64-row writes overflowing Ws1 into S -> absmax inf). Fixed.
// Load tier by alignment (wave-uniform): N%4==0 -> float4 (16B-aligned since
// n%4==0), N%2==0 -> float2 (8B-aligned; head N=2002), else scalar (Ws1
// N=40257). For N%4==0 & n%4==0: n+3<N <=> n<N, so full-load-or-zero is exact;
// same argument for float2 with even N.
__device__ __forceinline__ void transpose_tile(
    const float* __restrict__ W, unsigned short* __restrict__ Wt,
    int K, int N, int Npad, int nx, int rel, float scale,
    float (*tile)[33], int tid) {
  const int n0 = (rel % nx) * 32, k0 = (rel / nx) * 32;
  if ((N & 3) == 0) {          // float4 path: scale0, proj0, proj1
    const int lk = tid >> 3, ln = (tid & 7) << 2;
    const int n = n0 + ln;
    float4 v = make_float4(0.f, 0.f, 0.f, 0.f);
    if (n + 3 < N) v = *(const float4*)(W + (size_t)(k0 + lk) * N + n);
    tile[lk][ln]     = v.x * scale;
    tile[lk][ln + 1] = v.y * scale;
    tile[lk][ln + 2] = v.z * scale;
    tile[lk][ln + 3] = v.w * scale;
  } else if ((N & 1) == 0) {   // float2 path: head (N=2002)
    const int lk = tid >> 4, ln = (tid & 15) << 1;
#pragma unroll
    for (int i = 0; i < 32; i += 16) {
      const int n = n0 + ln;
      float2 v = make_float2(0.f, 0.f);
      if (n + 1 < N) v = *(const float2*)(W + (size_t)(k0 + lk + i) * N + n);
      tile[lk + i][ln]     = v.x * scale;
      tile[lk + i][ln + 1] = v.y * scale;
    }
  } else {                     // scalar path: scale1 (N odd)
    const int tx = tid & 31, ty = tid >> 5;
    for (int i = 0; i < 32; i += 8) {
      int k = k0 + ty + i, n = n0 + tx;
      tile[ty + i][tx] = (n < N) ? W[(size_t)k * N + n] * scale : 0.f;
    }
  }
  __syncthreads();
  // write: 32 n-rows x 4 ushort8 (16 B) stores = 128 threads
  if (tid < 128) {
    const int nloc = tid >> 2, kg = tid & 3;
    const int n = n0 + nloc;
    if (n < Npad) {
      ushort8 x;
#pragma unroll
      for (int j = 0; j < 8; j++) x[j] = f2bf(tile[kg * 8 + j][nloc]);
      *(ushort8*)&Wt[(size_t)n * K + k0 + kg * 8] = x;
    }
  }
}

// ---------------- prep: ALL dependency-free work in one launch --------------
#define PP_WH_END   2048                     // head: 64 x 32 tiles
#define PP_WS0_END  (PP_WH_END + 2016)       // scale0: 252 x 8
#define PP_WS1_END  (PP_WS0_END + 2520)      // scale1: 1260 x 2
#define PP_WP0_END  (PP_WS1_END + 256)       // proj0: 8 x 32
#define PP_WP1_END  (PP_WP0_END + 64)        // proj1: 2 x 32
#define PP_LB_END   (PP_WP1_END + 2048)      // logits cast
#define PP_ZERO_END (PP_LB_END + 32)         // Wp rows 320..383
#define PP_S_END    (PP_ZERO_END + 4)        // S zero
#define PP_TOTAL    (PP_S_END + 1)           // compact (single block)

__global__ __launch_bounds__(256) void prep_kernel(
    const float* __restrict__ head, const float* __restrict__ proj0,
    const float* __restrict__ proj1, const float* __restrict__ scale0,
    const float* __restrict__ scale1, const float* __restrict__ logits,
    const int* __restrict__ targets,
    unsigned short* __restrict__ Wh, unsigned short* __restrict__ Wp,
    unsigned short* __restrict__ Ws0, unsigned short* __restrict__ Ws1,
    unsigned short* __restrict__ Lb, float* __restrict__ S,
    int* __restrict__ idx0, int* __restrict__ idx1, int* __restrict__ cnt) {
  __shared__ float tile[32][33];
  const int id = blockIdx.x, tid = threadIdx.x;
  if (id < PP_WP1_END) {  // weight transposes
    const float* W; unsigned short* Wt; int K, N, Npad, nx, rel; float scale;
    if (id < PP_WH_END)        { W = head;   Wt = Wh;  K = 1024; N = ROOT_COLS; Npad = ROOT_PAD; scale = LOG2E; nx = 64;   rel = id; }
    else if (id < PP_WS0_END)  { W = scale0; Wt = Ws0; K = 256;  N = T0_COLS;   Npad = T0_PAD;   scale = LOG2E; nx = 252;  rel = id - PP_WH_END; }
    else if (id < PP_WS1_END)  { W = scale1; Wt = Ws1; K = 64;   N = T1_COLS;   Npad = T1_PAD;   scale = LOG2E; nx = 1260; rel = id - PP_WS0_END; }
    else if (id < PP_WP0_END)  { W = proj0;  Wt = Wp;  K = 1024; N = 256;       Npad = 256;      scale = 1.f;   nx = 8;    rel = id - PP_WS1_END; }
    else                       { W = proj1;  Wt = Wp + 256 * 1024; K = 1024; N = 64; Npad = 64; scale = 1.f; nx = 2; rel = id - PP_WP0_END; }
    transpose_tile(W, Wt, K, N, Npad, nx, rel, scale, tile, tid);
    return;
  }
  if (id < PP_LB_END) {  // logits f32 -> bf16, 2048 elements/block
    size_t base = (size_t)(id - PP_WP1_END) * 2048 + tid * 8;
    float4 v0 = *(const float4*)(logits + base);
    float4 v1 = *(const float4*)(logits + base + 4);
    ushort8 h;
    h[0] = f2bf(v0.x); h[1] = f2bf(v0.y); h[2] = f2bf(v0.z); h[3] = f2bf(v0.w);
    h[4] = f2bf(v1.x); h[5] = f2bf(v1.y); h[6] = f2bf(v1.z); h[7] = f2bf(v1.w);
    *(ushort8*)(Lb + base) = h;
    return;
  }
  if (id < PP_ZERO_END) {  // zero Wp rows 320..383
    size_t off = (size_t)(id - PP_LB_END) * 2048 + tid * 8;
    ushort8 z = {0, 0, 0, 0, 0, 0, 0, 0};
    *(ushort8*)(Wp + 320ull * 1024 + off) = z;
    return;
  }
  if (id < PP_S_END) {  // zero S (12288 floats over 4 blocks)
    int rel = id - PP_ZERO_END;
    float4 z = make_float4(0.f, 0.f, 0.f, 0.f);
#pragma unroll
    for (int j = 0; j < 3; j++)
      ((float4*)S)[rel * 768 + j * 256 + tid] = z;
    return;
  }
  // compact: one block, LDS counters (cnt written only here)
  __shared__ int base2[2];
  if (tid < 2) base2[tid] = 0;
  __syncthreads();
  for (int n = tid; n < NROWS; n += 256) {
    int t = targets[n];
    if (t >= T0_LO && t < T0_HI) idx0[atomicAdd(&base2[0], 1)] = n;
    else if (t >= T1_LO)         idx1[atomicAdd(&base2[1], 1)] = n;
  }
  __syncthreads();
  if (tid < 2) cnt[tid] = base2[tid];
}

// Shared 64-row x CI-cg x K=1024 MFMA K-loop (double-buffered KC=128 halves).
template<int CI>
__device__ __forceinline__ void gemm64_kloop(
    unsigned short* A_lds,   // 2 x (64*128) ushorts = 32 KB
    const unsigned short* Arow,
    const unsigned short* const (&Bbase)[CI],
    floatx4 (&acc)[CI][4], int tid) {
  const int lane = tid & 63, w = tid >> 6;
  const int m = lane & 15, quad = lane >> 4, keym = m & 7;
  int goff[4];
#pragma unroll
  for (int it = 0; it < 4; it++) {
    int s = w * 256 + it * 64 + lane;
    int r = s >> 4, p = s & 15;
    int cq = p ^ (r & 7);
    goff[it] = r * CDIM + cq * 8;
  }
#pragma unroll
  for (int it = 0; it < 4; it++)
    stage16(Arow + goff[it], &A_lds[(w * 256 + it * 64) * 8], lane);
  for (int h = 0; h < 8; h++) {
    unsigned short* cur = A_lds + (h & 1) * (64 * 128);
    unsigned short* nxt = A_lds + ((h + 1) & 1) * (64 * 128);
    __syncthreads();
    if (h + 1 < 8) {
#pragma unroll
      for (int it = 0; it < 4; it++)
        stage16(Arow + goff[it] + (h + 1) * 128,
                &nxt[(w * 256 + it * 64) * 8], lane);
    }
    short8 b[CI][4];
#pragma unroll
    for (int ci = 0; ci < CI; ci++)
#pragma unroll
      for (int ks = 0; ks < 4; ks++)
        b[ci][ks] = *(const short8*)(Bbase[ci] + h * 128 + ks * 32);
    short8 areg[4][4];
#pragma unroll
    for (int t = 0; t < 4; t++)
#pragma unroll
      for (int ks = 0; ks < 4; ks++) {
        int ch = ((ks << 2) + quad) ^ keym;
        areg[t][ks] = *(const short8*)&cur[(t * 16 + m) * 128 + (ch << 3)];
      }
#pragma unroll
    for (int ci = 0; ci < CI; ci++)
#pragma unroll
      for (int ks = 0; ks < 4; ks++)
#pragma unroll
        for (int t = 0; t < 4; t++)
          acc[ci][t] = mfma16(areg[t][ks], b[ci][ks], acc[ci][t]);
  }
}

// ---------------- hidden: Hb[4096][320] = bf16(Lb @ Wp), 320 blocks --------
__global__ __launch_bounds__(256) void hidden_kernel(
    const unsigned short* __restrict__ Lb,
    const unsigned short* __restrict__ Wp,
    unsigned short* __restrict__ Hb) {
  __shared__ unsigned short A_lds[64 * 256];  // 2 x 16 KB halves
  const int id = blockIdx.x, tid = threadIdx.x;
  const int xcd = id & 7, k = id >> 3;          // k in [0,40)
  const int row0 = (xcd * 8 + (k & 7)) * 64;
  const int cg0 = k >> 3;                       // [0,5)
  const int lane = tid & 63, w = tid >> 6;
  const int m = lane & 15, quad = lane >> 4;
  const floatx4 zf = {0.f, 0.f, 0.f, 0.f};
  floatx4 acc[1][4];
#pragma unroll
  for (int t = 0; t < 4; t++) acc[0][t] = zf;
  const unsigned short* Bb[1] = {
      Wp + (size_t)(cg0 * 64 + w * 16 + m) * CDIM + quad * 8};
  gemm64_kloop<1>(A_lds, Lb + (size_t)row0 * CDIM, Bb, acc, tid);
  int n = cg0 * 64 + w * 16 + m;
  if (n < HB_STRIDE) {
#pragma unroll
    for (int t = 0; t < 4; t++)
#pragma unroll
      for (int r = 0; r < 4; r++)
        Hb[(size_t)(row0 + t * 16 + quad * 4 + r) * HB_STRIDE + n] =
            f2bf(acc[0][t][r]);
  }
}

// ---------------- mega kernel (r1 structure: best measured, 84.5 us) --------
// XCD-sorted phases, FETCH ~= one-pass ideal (38 MB). r16 interleave and r17
// slim-reg variants both REGRESSED (93/95 us) -> reverted.
#define MG_ROOT 512           // 32 x-tiles (BM=128) x 16 cg-pairs
#define MG_T1   480           // 32 row-tiles (BM=128) x 15 y
#define MG_T0   2688          // 128 row-tiles x 21 y
#define MG_PICK 1024
#define MG_TOTAL (MG_ROOT + MG_T1 + MG_T0 + MG_PICK)

// Root CE, BM=128, KC=64 ping-pong double-buffer.
__device__ __forceinline__ void root_compute(
    const unsigned short* cur, const short8 (&b)[2][2], floatx4 (&acc)[2][8],
    int m, int quad, int keym) {
#pragma unroll
  for (int hf = 0; hf < 2; hf++) {
    short8 areg[4][2];
#pragma unroll
    for (int t = 0; t < 4; t++)
#pragma unroll
      for (int ks = 0; ks < 2; ks++) {
        int ch = ((ks << 2) + quad) ^ keym;
        areg[t][ks] = *(const short8*)&cur[(hf * 64 + t * 16 + m) * 64 + (ch << 3)];
      }
#pragma unroll
    for (int ci = 0; ci < 2; ci++)
#pragma unroll
      for (int ks = 0; ks < 2; ks++)
#pragma unroll
        for (int t = 0; t < 4; t++)
          acc[ci][hf * 4 + t] = mfma16(areg[t][ks], b[ci][ks], acc[ci][hf * 4 + t]);
  }
}

__device__ __forceinline__ void root_stage(
    const unsigned short* Arow, const int (&goff)[4], int koff,
    unsigned short* buf, int w, int lane) {
#pragma unroll
  for (int it = 0; it < 4; it++)
    stage16(Arow + goff[it] + koff, &buf[(it * 256 + w * 64) * 8], lane);
}

__device__ __forceinline__ void root_loadB(
    const unsigned short* const (&Bb)[2], int koff, short8 (&b)[2][2]) {
#pragma unroll
  for (int ci = 0; ci < 2; ci++)
#pragma unroll
    for (int ks = 0; ks < 2; ks++)
      b[ci][ks] = *(const short8*)(Bb[ci] + koff + ks * 32);
}

__device__ __forceinline__ void root_path(
    unsigned char* smem, int bx, int by,
    const unsigned short* __restrict__ Lb,
    const unsigned short* __restrict__ Wh, float* __restrict__ S) {
  unsigned short* bufA = (unsigned short*)smem;   // 128 rows x 64 k = 16 KB
  unsigned short* bufB = bufA + 128 * 64;         // second half
  const int tid = threadIdx.x;
  const int row0 = bx * 128;
  const int cg0 = by * 2;
  const int lane = tid & 63, w = tid >> 6;
  const int m = lane & 15, quad = lane >> 4, keym = m & 7;
  const floatx4 zf = {0.f, 0.f, 0.f, 0.f};
  floatx4 acc[2][8];
#pragma unroll
  for (int ci = 0; ci < 2; ci++)
#pragma unroll
    for (int t = 0; t < 8; t++) acc[ci][t] = zf;
  const unsigned short* Bb[2] = {
      Wh + (size_t)((cg0 + 0) * 64 + w * 16 + m) * CDIM + quad * 8,
      Wh + (size_t)((cg0 + 1) * 64 + w * 16 + m) * CDIM + quad * 8};
  const unsigned short* Arow = Lb + (size_t)row0 * CDIM;
  // staging: slot s = it*256 + w*64 + lane -> row r = s>>3 (8 chunks/row of
  // 16 B), phys p = s&7 stores logical cq = p^(r&7) (XOR bank swizzle)
  int goff[4];
#pragma unroll
  for (int it = 0; it < 4; it++) {
    int s = it * 256 + w * 64 + lane;
    int r = s >> 3, p = s & 7;
    int cq = p ^ (r & 7);
    goff[it] = r * CDIM + cq * 8;
  }
  short8 b0[2][2], b1[2][2];
  root_stage(Arow, goff, 0, bufA, w, lane);   // chunk 0 in flight
  root_loadB(Bb, 0, b0);
  for (int hh = 0; hh < 8; hh++) {
    __syncthreads();                          // drains chunk 2hh into bufA
    root_stage(Arow, goff, (hh * 2 + 1) * 64, bufB, w, lane);
    root_loadB(Bb, (hh * 2 + 1) * 64, b1);
    root_compute(bufA, b0, acc, m, quad, keym);
    __syncthreads();                          // drains chunk 2hh+1 into bufB
    if (hh < 7) {
      root_stage(Arow, goff, (hh * 2 + 2) * 64, bufA, w, lane);
      root_loadB(Bb, (hh * 2 + 2) * 64, b0);
    }
    root_compute(bufB, b1, acc, m, quad, keym);
  }
  // epilogue: reuse smem for 128 per-row sums
  __syncthreads();
  float* sums = (float*)smem;
  if (tid < 128) sums[tid] = 0.f;
  __syncthreads();
#pragma unroll
  for (int t = 0; t < 8; t++)
#pragma unroll
    for (int r = 0; r < 4; r++) {
      float e = __builtin_amdgcn_exp2f(acc[0][t][r]) +
                __builtin_amdgcn_exp2f(acc[1][t][r]);
      e += __shfl_xor(e, 1); e += __shfl_xor(e, 2);
      e += __shfl_xor(e, 4); e += __shfl_xor(e, 8);
      if (m == 0)
        atomicAdd(&sums[(t >> 2) * 64 + (t & 3) * 16 + quad * 4 + r], e);
    }
  __syncthreads();
  if (tid < 128) atomicAdd(&S[row0 + tid], sums[tid]);
}

// Tail CE path: A in regs, runtime cg loop, 2 cgs/iter through literally-
// indexed b0/b1 with 2-deep prefetch.
template<int K, int TILES, int MODE>
__device__ __forceinline__ void tail_path(
    unsigned char* smem, int bx, int by,
    const unsigned short* __restrict__ Hb, int acol0,
    const unsigned short* __restrict__ Wt, int ncgpb,
    const int* __restrict__ idx, const int* __restrict__ cnt,
    float* __restrict__ S) {
  constexpr int BM = TILES * 16;
  constexpr int CpR = K / 8;
  constexpr int KS = K / 32;
  unsigned short* A_lds = (unsigned short*)smem;            // BM*K ushorts
  int* row_lds = (int*)(smem + (size_t)BM * K * 2);
  float* sum_lds = (float*)(smem + (size_t)BM * K * 2 + BM * 4);
  const int tid = threadIdx.x;
  const int count = cnt[MODE - 1];
  const int row0 = bx * BM;
  if (row0 >= count) return;
  if (tid < BM) {
    int r = row0 + tid;
    row_lds[tid] = (r < count) ? idx[r] : -1;
    sum_lds[tid] = 0.f;
  }
  __syncthreads();
#pragma unroll
  for (int i = 0; i < BM * CpR / 256; i++) {
    int c = tid + 256 * i;
    int rl = c / CpR, cq = c % CpR;
    int row = row_lds[rl];
    ushort8 v = {0, 0, 0, 0, 0, 0, 0, 0};
    if (row >= 0) v = *(const ushort8*)(Hb + (size_t)row * HB_STRIDE + acol0 + cq * 8);
    *(ushort8*)&A_lds[rl * K + ((cq ^ (rl & 7)) << 3)] = v;
  }
  __syncthreads();
  const int lane = tid & 63, w = tid >> 6;
  const int m = lane & 15, quad = lane >> 4, keym = m & 7;
  const floatx4 zf = {0.f, 0.f, 0.f, 0.f};
  short8 areg[TILES][KS];
#pragma unroll
  for (int t = 0; t < TILES; t++)
#pragma unroll
    for (int ks = 0; ks < KS; ks++) {
      int ch = ((ks << 2) + quad) ^ keym;
      areg[t][ks] = *(const short8*)&A_lds[(t * 16 + m) * K + (ch << 3)];
    }
  float runsum[TILES][4];
#pragma unroll
  for (int t = 0; t < TILES; t++)
#pragma unroll
    for (int r = 0; r < 4; r++) runsum[t][r] = 0.f;

  const int cg0 = by * ncgpb;
  const unsigned short* Bp = Wt + (size_t)(cg0 * 64 + w * 16 + m) * K + quad * 8;
  short8 b0[KS], b1[KS];
#pragma unroll
  for (int ks = 0; ks < KS; ks++) b0[ks] = *(const short8*)(Bp + ks * 32);
#pragma unroll
  for (int ks = 0; ks < KS; ks++)
    b1[ks] = *(const short8*)(Bp + (size_t)64 * K + ks * 32);

  for (int cc = 0; cc < ncgpb; cc += 2) {  // runtime loop, literal reg indices
    floatx4 acc[TILES];
#pragma unroll
    for (int t = 0; t < TILES; t++) acc[t] = zf;
#pragma unroll
    for (int ks = 0; ks < KS; ks++)
#pragma unroll
      for (int t = 0; t < TILES; t++) acc[t] = mfma16(areg[t][ks], b0[ks], acc[t]);
    if (cc + 2 < ncgpb) {
      const unsigned short* p = Bp + (size_t)(cc + 2) * 64 * K;
#pragma unroll
      for (int ks = 0; ks < KS; ks++) b0[ks] = *(const short8*)(p + ks * 32);
    }
#pragma unroll
    for (int t = 0; t < TILES; t++)
#pragma unroll
      for (int r = 0; r < 4; r++)
        runsum[t][r] += __builtin_amdgcn_exp2f(acc[t][r]);

#pragma unroll
    for (int t = 0; t < TILES; t++) acc[t] = zf;
#pragma unroll
    for (int ks = 0; ks < KS; ks++)
#pragma unroll
      for (int t = 0; t < TILES; t++) acc[t] = mfma16(areg[t][ks], b1[ks], acc[t]);
    if (cc + 3 < ncgpb) {
      const unsigned short* p = Bp + (size_t)(cc + 3) * 64 * K;
#pragma unroll
      for (int ks = 0; ks < KS; ks++) b1[ks] = *(const short8*)(p + ks * 32);
    }
#pragma unroll
    for (int t = 0; t < TILES; t++)
#pragma unroll
      for (int r = 0; r < 4; r++)
        runsum[t][r] += __builtin_amdgcn_exp2f(acc[t][r]);
  }

#pragma unroll
  for (int t = 0; t < TILES; t++)
#pragma unroll
    for (int r = 0; r < 4; r++) {
      float e = runsum[t][r];
      e += __shfl_xor(e, 1); e += __shfl_xor(e, 2);
      e += __shfl_xor(e, 4); e += __shfl_xor(e, 8);
      if (m == 0) atomicAdd(&sum_lds[t * 16 + quad * 4 + r], e);
    }
  __syncthreads();
  if (tid < BM) {
    int row = row_lds[tid];
    if (row >= 0) atomicAdd(&S[row], sum_lds[tid]);
  }
}

__device__ __forceinline__ void picked_path(
    int rel, const float* __restrict__ logits, const int* __restrict__ targets,
    const unsigned short* __restrict__ Wh,
    const unsigned short* __restrict__ Ws0,
    const unsigned short* __restrict__ Ws1,
    const unsigned short* __restrict__ Hb, float* __restrict__ P) {
  const int tid = threadIdx.x, lane = tid & 63;
  const int row = rel * 4 + (tid >> 6);
  const int t = targets[row];
  const int tr = (t >= T0_LO && t < T0_HI) ? T0_LO : ((t >= T1_LO) ? T0_LO + 1 : t);
  const float* a = logits + (size_t)row * CDIM + lane * 16;
  const unsigned short* wr = Wh + (size_t)tr * CDIM + lane * 16;
  float acc = 0.f;
#pragma unroll
  for (int q = 0; q < 2; q++) {
    ushort8 wv = *(const ushort8*)(wr + q * 8);
    float4 a0 = ((const float4*)a)[q * 2];
    float4 a1 = ((const float4*)a)[q * 2 + 1];
    acc += a0.x * bf2f(wv[0]) + a0.y * bf2f(wv[1]) + a0.z * bf2f(wv[2]) + a0.w * bf2f(wv[3]);
    acc += a1.x * bf2f(wv[4]) + a1.y * bf2f(wv[5]) + a1.z * bf2f(wv[6]) + a1.w * bf2f(wv[7]);
  }
#pragma unroll
  for (int off = 1; off < 64; off <<= 1) acc += __shfl_xor(acc, off);
  if (lane == 0) P[row] = acc * LN2;
  if (t >= T0_LO) {
    float acc2 = 0.f;
    if (t < T0_HI) {
      const unsigned short* h = Hb + (size_t)row * HB_STRIDE + lane * 4;
      const unsigned short* w2 = Ws0 + (size_t)(t - T0_LO) * 256 + lane * 4;
#pragma unroll
      for (int j = 0; j < 4; j++) acc2 += bf2f(h[j]) * bf2f(w2[j]);
    } else {
      acc2 = bf2f(Hb[(size_t)row * HB_STRIDE + 256 + lane]) *
             bf2f(Ws1[(size_t)(t - T1_LO) * 64 + lane]);
    }
#pragma unroll
    for (int off = 1; off < 64; off <<= 1) acc2 += __shfl_xor(acc2, off);
    if (lane == 0) P[(t < T0_HI ? NROWS : 2 * NROWS) + row] = acc2 * LN2;
  }
}

__global__ __launch_bounds__(256, 2) void mega_kernel(
    const unsigned short* __restrict__ Lb,
    const unsigned short* __restrict__ Wh,
    const unsigned short* __restrict__ Ws0,
    const unsigned short* __restrict__ Ws1,
    const unsigned short* __restrict__ Hb,
    const float* __restrict__ logits, const int* __restrict__ targets,
    const int* __restrict__ idx0, const int* __restrict__ idx1,
    const int* __restrict__ cnt, float* __restrict__ S, float* __restrict__ P) {
  __shared__ __align__(16) unsigned char smem[32768];
  int bid = blockIdx.x;
  if (bid < MG_ROOT) {
    // XCD remap: each XCD owns a contiguous 64-block chunk, y-fastest.
    int wk = ((bid & 7) << 6) + (bid >> 3);      // [0,512) bijective
    root_path(smem, wk >> 4, wk & 15, Lb, Wh, S);
    return;
  }
  bid -= MG_ROOT;
  if (bid < MG_T1) {
    int wk = (bid & 7) * 60 + (bid >> 3);        // [0,480) bijective
    tail_path<64, 8, 2>(smem, wk & 31, wk >> 5, Hb, 256, Ws1, 42, idx1, cnt,
                        S + 2 * NROWS);
    return;
  }
  bid -= MG_T1;
  if (bid < MG_T0) {
    int wk = (bid & 7) * 336 + (bid >> 3);       // [0,2688) bijective
    tail_path<256, 2, 1>(smem, wk & 127, wk >> 7, Hb, 0, Ws0, 6, idx0, cnt,
                         S + NROWS);
    return;
  }
  bid -= MG_T0;
  picked_path(bid, logits, targets, Wh, Ws0, Ws1, Hb, P);
}

__global__ __launch_bounds__(1024) void loss_kernel(
    const int* __restrict__ targets,
    const float* __restrict__ S,   // [3][NROWS]
    const float* __restrict__ P,   // [3][NROWS]
    float* __restrict__ out) {
  const int tid = threadIdx.x;
  float sr = 0.f, s0 = 0.f, s1 = 0.f, c0 = 0.f, c1 = 0.f;
  for (int n = tid; n < NROWS; n += 1024) {
    int t = targets[n];
    sr += logf(S[n] - 46.f) - P[n];  // 46 root pad cols -> exp2(0)=1 each
    if (t >= T0_LO && t < T0_HI) { s0 += logf(S[NROWS + n] - 64.f) - P[NROWS + n]; c0 += 1.f; }
    else if (t >= T1_LO)         { s1 += logf(S[2 * NROWS + n] - 63.f) - P[2 * NROWS + n]; c1 += 1.f; }
  }
  for (int off = 32; off > 0; off >>= 1) {
    sr += __shfl_down(sr, off);
    s0 += __shfl_down(s0, off);
    s1 += __shfl_down(s1, off);
    c0 += __shfl_down(c0, off);
    c1 += __shfl_down(c1, off);
  }
  __shared__ float red[16][5];
  int wv = tid >> 6;
  if ((tid & 63) == 0) { red[wv][0] = sr; red[wv][1] = s0; red[wv][2] = s1; red[wv][3] = c0; red[wv][4] = c1; }
  __syncthreads();
  if (tid == 0) {
    sr = 0.f; s0 = 0.f; s1 = 0.f; c0 = 0.f; c1 = 0.f;
#pragma unroll
    for (int i = 0; i < 16; i++) {
      sr += red[i][0]; s0 += red[i][1]; s1 += red[i][2];
      c0 += red[i][3]; c1 += red[i][4];
    }
    float root_loss = sr / (float)NROWS;
    float l0 = s0 / fmaxf(c0, 1.f);
    float l1 = s1 / fmaxf(c1, 1.f);
    out[0] = (root_loss + l0 + l1) / 3.f;
  }
}

extern "C" void kernel_launch(void* const* d_in, const int* in_sizes, int n_in,
                              void* d_out, int out_size, void* d_ws, size_t ws_size,
                              hipStream_t stream) {
  const float* logits  = (const float*)d_in[0];
  const int*   targets = (const int*)d_in[1];
  const float* head    = (const float*)d_in[2];
  const float* proj0   = (const float*)d_in[3];
  const float* scale0  = (const float*)d_in[4];
  const float* proj1   = (const float*)d_in[5];
  const float* scale1  = (const float*)d_in[6];
  float* out = (float*)d_out;
  char* ws = (char*)d_ws;

  unsigned short* Hb  = (unsigned short*)(ws + B_HB);
  unsigned short* Lb  = (unsigned short*)(ws + B_LB);
  unsigned short* Wp  = (unsigned short*)(ws + B_WP);
  unsigned short* Wh  = (unsigned short*)(ws + B_WH);
  unsigned short* Ws0 = (unsigned short*)(ws + B_WS0);
  unsigned short* Ws1 = (unsigned short*)(ws + B_WS1);
  float* S = (float*)(ws + B_S);
  float* P = (float*)(ws + B_P);
  int* idx0 = (int*)(ws + B_I0);
  int* idx1 = (int*)(ws + B_I1);
  int* cnt  = (int*)(ws + B_CNT);

  prep_kernel<<<PP_TOTAL, 256, 0, stream>>>(head, proj0, proj1, scale0, scale1,
                                            logits, targets, Wh, Wp, Ws0, Ws1,
                                            Lb, S, idx0, idx1, cnt);
  hidden_kernel<<<320, 256, 0, stream>>>(Lb, Wp, Hb);
  mega_kernel<<<MG_TOTAL, 256, 0, stream>>>(Lb, Wh, Ws0, Ws1, Hb, logits,
                                            targets, idx0, idx1, cnt, S, P);
  loss_kernel<<<1, 1024, 0, stream>>>(targets, S, P, out);
}